// Round 1
// baseline (589.183 us; speedup 1.0000x reference)
//
#include <hip/hip_runtime.h>
#include <cstddef>

typedef float vf4 __attribute__((ext_vector_type(4)));

// ---- workspace layout (floats) ----
#define OFF_W    0
#define OFF_Z    1024
#define OFF_B    2048
#define OFF_V    3072
#define OFF_K    4096
#define OFF_Q    5120
#define OFF_AL   5248
#define OFF_BA   6272
#define OFF_U    7296
#define OFF_CW   8320
#define OFF_ALP  9344
#define OFF_CB   10368
#define OFF_CV   11392
#define OFF_BSD  12416
#define OFF_YH   13440

// output layout (floats): y[512] | S_new[131072] | sm_{w,z,b,v,k}_n[5 x 16777216]
#define OUT_SNEW 512
#define OUT_BIG  131584
#define BIGSZ    16777216

__device__ __forceinline__ float sigm(float x) { return 1.0f / (1.0f + expf(-x)); }

// ---- K1: projections. rows 0..5119 -> W_{w,z,b,v,k}, rows 5120..5247 -> W_q ----
__global__ __launch_bounds__(256) void k_proj(
    const float* __restrict__ x,
    const float* __restrict__ Ww, const float* __restrict__ Wz,
    const float* __restrict__ Wb, const float* __restrict__ Wv,
    const float* __restrict__ Wk, const float* __restrict__ Wq,
    float* __restrict__ ws)
{
    int wave = threadIdx.x >> 6;
    int lane = threadIdx.x & 63;
    int row  = blockIdx.x * 4 + wave;          // 0..5247 (grid = 1312 blocks exactly)
    const float* W;
    float* dst;
    if (row < 5120) {
        int t = row >> 10;                     // which weight matrix
        int r = row & 1023;
        const float* Ws[5] = {Ww, Wz, Wb, Wv, Wk};
        W = Ws[t] + (size_t)r * 512;
        dst = ws + t * 1024 + r;
    } else {
        int r = row - 5120;
        W = Wq + (size_t)r * 512;
        dst = ws + OFF_Q + r;
    }
    float s = 0.f;
#pragma unroll
    for (int e = 0; e < 8; ++e)
        s += W[lane + 64 * e] * x[lane + 64 * e];
#pragma unroll
    for (int off = 32; off; off >>= 1)
        s += __shfl_down(s, off, 64);
    if (lane == 0) *dst = s;
}

// ---- K2: per-head scalars, S_new, y_heads. grid = 8 blocks x 128 threads ----
__global__ __launch_bounds__(128) void k_head(
    const float* __restrict__ S,
    float* __restrict__ ws,
    float* __restrict__ out)
{
    int h = blockIdx.x;
    int i = threadIdx.x;          // 0..127
    int hi = h * 128 + i;

    __shared__ vf4 kk4[32];
    __shared__ vf4 qq4[32];
    float* kkf = (float*)kk4;
    float* qqf = (float*)qq4;

    float w = ws[OFF_W + hi];
    float z = ws[OFF_Z + hi];
    float b = ws[OFF_B + hi];
    float v = ws[OFF_V + hi];
    kkf[i] = ws[OFF_K + hi];
    qqf[i] = ws[OFF_Q + i];
    __syncthreads();

    // s_dot[i] = sum_j S[h,i,j] * k[h,j]   (row cached in registers)
    const vf4* S4 = reinterpret_cast<const vf4*>(S + (size_t)hi * 128);
    vf4 srow[32];
    float sd = 0.f;
#pragma unroll
    for (int j4 = 0; j4 < 32; ++j4) {
        vf4 sv = S4[j4];
        srow[j4] = sv;
        vf4 kv = kk4[j4];
        sd += sv.x * kv.x + sv.y * kv.y + sv.z * kv.z + sv.w * kv.w;
    }

    float g  = sigm(w);
    float al = sigm(z);
    float be = sigm(b);
    float r  = al * sd;           // r = al * s_dot
    float gv = g * v;
    float u  = be * (gv - r);
    float ba = be * al;

    ws[OFF_AL  + hi] = al;
    ws[OFF_BA  + hi] = ba;
    ws[OFF_U   + hi] = u;
    ws[OFF_CW  + hi] = be * g * (1.f - g) * v;     // be*gp*v
    ws[OFF_ALP + hi] = al * (1.f - al);            // alp
    ws[OFF_CB  + hi] = be * (1.f - be) * (gv - r); // bep*(g*v - r)
    ws[OFF_CV  + hi] = be * g;
    ws[OFF_BSD + hi] = be * sd;

    // S_new[i][j] = al[i]*S[i][j] + u[i]*k[j];  y_head[i] = S_new[i][:] . q
    vf4* O4 = reinterpret_cast<vf4*>(out + OUT_SNEW + (size_t)hi * 128);
    float yh = 0.f;
#pragma unroll
    for (int j4 = 0; j4 < 32; ++j4) {
        vf4 sn = al * srow[j4] + u * kk4[j4];
        O4[j4] = sn;
        vf4 qv = qq4[j4];
        yh += sn.x * qv.x + sn.y * qv.y + sn.z * qv.z + sn.w * qv.w;
    }
    ws[OFF_YH + hi] = yh;
}

// ---- K3: the big streaming kernel. grid = 5*1024 blocks x 256 threads ----
// block = (tensor t, h, i); slice P[h,i,:,:] is 128(j) x 128(c)
__global__ __launch_bounds__(256) void k_main(
    const float* __restrict__ smw, const float* __restrict__ smz,
    const float* __restrict__ smb, const float* __restrict__ smv,
    const float* __restrict__ smk, const float* __restrict__ S,
    const float* __restrict__ ws, float* __restrict__ out)
{
    int bid = blockIdx.x;
    int t   = bid >> 10;            // 0..4
    int hi  = bid & 1023;
    int h   = hi >> 7;
    int i   = hi & 127;

    const float* Ps[5] = {smw, smz, smb, smv, smk};
    const float* P = Ps[t] + (size_t)hi * 16384;
    float* O = out + OUT_BIG + (size_t)t * BIGSZ + (size_t)hi * 16384;

    int tid = threadIdx.x;
    int tj  = tid >> 5;             // 0..7  (row group)
    int tc  = tid & 31;             // 0..31 (float4 column group)

    __shared__ vf4 kk4[32];
    __shared__ vf4 red[8][32];
    float* kkf = (float*)kk4;
    if (tid < 128) kkf[tid] = ws[OFF_K + h * 128 + tid];
    __syncthreads();

    // pass 1: load slice into registers, partial contr
    const vf4* P4 = reinterpret_cast<const vf4*>(P);
    vf4 p[16];
    vf4 acc = {0.f, 0.f, 0.f, 0.f};
#pragma unroll
    for (int m = 0; m < 16; ++m) {
        int j = tj + (m << 3);
        vf4 pv = P4[j * 32 + tc];
        p[m] = pv;
        acc += kkf[j] * pv;
    }
    red[tj][tc] = acc;
    __syncthreads();
    if (tj == 0) {
        vf4 c = red[0][tc];
#pragma unroll
        for (int rr = 1; rr < 8; ++rr) c += red[rr][tc];
        red[0][tc] = c;
    }
    __syncthreads();
    vf4 contr = red[0][tc];

    float al_i = ws[OFF_AL + hi];
    float ba_i = ws[OFF_BA + hi];

    float coef = 0.f, bsd_i = 0.f, u_i = 0.f;
    vf4 scol = {0.f, 0.f, 0.f, 0.f};
    float srow[16];
    int ic = i >> 2, icomp = i & 3;

    if (t == 0)      coef = ws[OFF_CW + hi];
    else if (t == 2) coef = ws[OFF_CB + hi];
    else if (t == 3) coef = ws[OFF_CV + hi];
    else if (t == 1) {
        coef  = ws[OFF_ALP + hi];
        bsd_i = ws[OFF_BSD + hi];
        if (tc == ic) {
#pragma unroll
            for (int m = 0; m < 16; ++m)
                srow[m] = S[(size_t)hi * 128 + tj + (m << 3)];
        }
    } else { // t == 4
        u_i  = ws[OFF_U + hi];
        scol = reinterpret_cast<const vf4*>(S + (size_t)hi * 128)[tc];
    }

    // pass 2: out[j][c] = al*P - ba*k[j]*contr[c] + D-term
    vf4* O4 = reinterpret_cast<vf4*>(O);
#pragma unroll
    for (int m = 0; m < 16; ++m) {
        int j = tj + (m << 3);
        float kj = kkf[j];
        vf4 o = al_i * p[m] - (ba_i * kj) * contr;
        if (t == 4) {
            o -= (ba_i * kj) * scol;              // -ba[i]*S[i,c]*k[j]
            if ((j >> 2) == tc) o[j & 3] += u_i;  // +u[i]*eye[j,c]
        } else if (t == 1) {
            if (tc == ic) o[icomp] += coef * (srow[m] - bsd_i * kj);
        } else {
            if (tc == ic) o[icomp] += coef * kj;  // eye[i,c] * coef * k[j]
        }
        O4[j * 32 + tc] = o;
    }
}

// ---- K4: y = W_o @ y_heads + b_o. grid = 128 blocks x 256 threads ----
__global__ __launch_bounds__(256) void k_out(
    const float* __restrict__ Wo, const float* __restrict__ bo,
    const float* __restrict__ ws, float* __restrict__ out)
{
    int wave = threadIdx.x >> 6;
    int lane = threadIdx.x & 63;
    int o = blockIdx.x * 4 + wave;     // 0..511
    const float* wr = Wo + (size_t)o * 1024;
    const float* yh = ws + OFF_YH;
    float s = 0.f;
#pragma unroll
    for (int e = 0; e < 16; ++e)
        s += wr[lane + 64 * e] * yh[lane + 64 * e];
#pragma unroll
    for (int off = 32; off; off >>= 1)
        s += __shfl_down(s, off, 64);
    if (lane == 0) out[o] = s + bo[o];
}

extern "C" void kernel_launch(void* const* d_in, const int* in_sizes, int n_in,
                              void* d_out, int out_size, void* d_ws, size_t ws_size,
                              hipStream_t stream)
{
    const float* x   = (const float*)d_in[0];
    const float* S   = (const float*)d_in[1];
    const float* smw = (const float*)d_in[2];
    const float* smz = (const float*)d_in[3];
    const float* smb = (const float*)d_in[4];
    const float* smv = (const float*)d_in[5];
    const float* smk = (const float*)d_in[6];
    const float* Ww  = (const float*)d_in[7];
    const float* Wz  = (const float*)d_in[8];
    const float* Wb  = (const float*)d_in[9];
    const float* Wv  = (const float*)d_in[10];
    const float* Wk  = (const float*)d_in[11];
    const float* Wq  = (const float*)d_in[12];
    const float* Wo  = (const float*)d_in[13];
    const float* bo  = (const float*)d_in[14];

    float* out = (float*)d_out;
    float* ws  = (float*)d_ws;

    k_proj<<<1312, 256, 0, stream>>>(x, Ww, Wz, Wb, Wv, Wk, Wq, ws);
    k_head<<<8, 128, 0, stream>>>(S, ws, out);
    k_main<<<5120, 256, 0, stream>>>(smw, smz, smb, smv, smk, S, ws, out);
    k_out<<<128, 256, 0, stream>>>(Wo, bo, ws, out);
}

// Round 2
// 564.903 us; speedup vs baseline: 1.0430x; 1.0430x over previous
//
#include <hip/hip_runtime.h>
#include <cstddef>

typedef float vf4 __attribute__((ext_vector_type(4)));

// ---- workspace layout (floats) ----
#define OFF_W    0
#define OFF_Z    1024
#define OFF_B    2048
#define OFF_V    3072
#define OFF_K    4096
#define OFF_Q    5120
#define OFF_AL   5248
#define OFF_BA   6272
#define OFF_U    7296
#define OFF_CW   8320
#define OFF_ALP  9344
#define OFF_CB   10368
#define OFF_CV   11392
#define OFF_BSD  12416
#define OFF_YH   13440

// output layout (floats): y[512] | S_new[131072] | sm_{w,z,b,v,k}_n[5 x 16777216]
#define OUT_SNEW 512
#define OUT_BIG  131584
#define BIGSZ    16777216

__device__ __forceinline__ float sigm(float x) { return 1.0f / (1.0f + expf(-x)); }

// ---- K1: projections. rows 0..5119 -> W_{w,z,b,v,k}, rows 5120..5247 -> W_q ----
__global__ __launch_bounds__(256) void k_proj(
    const float* __restrict__ x,
    const float* __restrict__ Ww, const float* __restrict__ Wz,
    const float* __restrict__ Wb, const float* __restrict__ Wv,
    const float* __restrict__ Wk, const float* __restrict__ Wq,
    float* __restrict__ ws)
{
    int wave = threadIdx.x >> 6;
    int lane = threadIdx.x & 63;
    int row  = blockIdx.x * 4 + wave;          // 0..5247 (grid = 1312 blocks exactly)
    const float* W;
    float* dst;
    if (row < 5120) {
        int t = row >> 10;                     // which weight matrix
        int r = row & 1023;
        const float* Ws[5] = {Ww, Wz, Wb, Wv, Wk};
        W = Ws[t] + (size_t)r * 512;
        dst = ws + t * 1024 + r;
    } else {
        int r = row - 5120;
        W = Wq + (size_t)r * 512;
        dst = ws + OFF_Q + r;
    }
    float s = 0.f;
#pragma unroll
    for (int e = 0; e < 8; ++e)
        s += W[lane + 64 * e] * x[lane + 64 * e];
#pragma unroll
    for (int off = 32; off; off >>= 1)
        s += __shfl_down(s, off, 64);
    if (lane == 0) *dst = s;
}

// ---- K2: per-head scalars, S_new, y_heads. grid = 8 blocks x 128 threads ----
__global__ __launch_bounds__(128) void k_head(
    const float* __restrict__ S,
    float* __restrict__ ws,
    float* __restrict__ out)
{
    int h = blockIdx.x;
    int i = threadIdx.x;          // 0..127
    int hi = h * 128 + i;

    __shared__ vf4 kk4[32];
    __shared__ vf4 qq4[32];
    float* kkf = (float*)kk4;
    float* qqf = (float*)qq4;

    float w = ws[OFF_W + hi];
    float z = ws[OFF_Z + hi];
    float b = ws[OFF_B + hi];
    float v = ws[OFF_V + hi];
    kkf[i] = ws[OFF_K + hi];
    qqf[i] = ws[OFF_Q + i];
    __syncthreads();

    // s_dot[i] = sum_j S[h,i,j] * k[h,j]   (row cached in registers)
    const vf4* S4 = reinterpret_cast<const vf4*>(S + (size_t)hi * 128);
    vf4 srow[32];
    float sd = 0.f;
#pragma unroll
    for (int j4 = 0; j4 < 32; ++j4) {
        vf4 sv = S4[j4];
        srow[j4] = sv;
        vf4 kv = kk4[j4];
        sd += sv.x * kv.x + sv.y * kv.y + sv.z * kv.z + sv.w * kv.w;
    }

    float g  = sigm(w);
    float al = sigm(z);
    float be = sigm(b);
    float r  = al * sd;           // r = al * s_dot
    float gv = g * v;
    float u  = be * (gv - r);
    float ba = be * al;

    ws[OFF_AL  + hi] = al;
    ws[OFF_BA  + hi] = ba;
    ws[OFF_U   + hi] = u;
    ws[OFF_CW  + hi] = be * g * (1.f - g) * v;     // be*gp*v
    ws[OFF_ALP + hi] = al * (1.f - al);            // alp
    ws[OFF_CB  + hi] = be * (1.f - be) * (gv - r); // bep*(g*v - r)
    ws[OFF_CV  + hi] = be * g;
    ws[OFF_BSD + hi] = be * sd;

    // S_new[i][j] = al[i]*S[i][j] + u[i]*k[j];  y_head[i] = S_new[i][:] . q
    vf4* O4 = reinterpret_cast<vf4*>(out + OUT_SNEW + (size_t)hi * 128);
    float yh = 0.f;
#pragma unroll
    for (int j4 = 0; j4 < 32; ++j4) {
        vf4 sn = al * srow[j4] + u * kk4[j4];
        O4[j4] = sn;
        vf4 qv = qq4[j4];
        yh += sn.x * qv.x + sn.y * qv.y + sn.z * qv.z + sn.w * qv.w;
    }
    ws[OFF_YH + hi] = yh;
}

// ---- K3: the big streaming kernel. grid = 5*1024 blocks x 1024 threads ----
// block = (tensor t, h, i); slice P[h,i,:,:] is 128(j) x 128(c)
// 1024 threads: tj = tid>>5 (row group 0..31), tc = tid&31 (vf4 column 0..31)
// each thread holds 4 vf4 of payload -> <=64 VGPRs -> 8 waves/SIMD
__global__ __launch_bounds__(1024, 8) void k_main(
    const float* __restrict__ smw, const float* __restrict__ smz,
    const float* __restrict__ smb, const float* __restrict__ smv,
    const float* __restrict__ smk, const float* __restrict__ S,
    const float* __restrict__ ws, float* __restrict__ out)
{
    int bid = blockIdx.x;
    int t   = bid >> 10;            // 0..4
    int hi  = bid & 1023;
    int h   = hi >> 7;
    int i   = hi & 127;

    const float* Ps[5] = {smw, smz, smb, smv, smk};
    const float* P = Ps[t] + (size_t)hi * 16384;
    float* O = out + OUT_BIG + (size_t)t * BIGSZ + (size_t)hi * 16384;

    int tid = threadIdx.x;
    int tj  = tid >> 5;             // 0..31 (row group)
    int tc  = tid & 31;             // 0..31 (float4 column group)

    __shared__ float kkf[128];
    __shared__ vf4 red[16][32];
    __shared__ vf4 contrS[32];
    if (tid < 128) kkf[tid] = ws[OFF_K + h * 128 + tid];
    __syncthreads();

    // pass 1: load slice into registers (nontemporal), partial contr
    const vf4* P4 = reinterpret_cast<const vf4*>(P);
    vf4 p[4];
    vf4 acc = {0.f, 0.f, 0.f, 0.f};
#pragma unroll
    for (int m = 0; m < 4; ++m) {
        int j = tj + (m << 5);
        vf4 pv = __builtin_nontemporal_load(P4 + j * 32 + tc);
        p[m] = pv;
        acc += kkf[j] * pv;
    }
    // combine the two half-wave row groups (same tc, lane ^ 32)
    acc.x += __shfl_xor(acc.x, 32, 64);
    acc.y += __shfl_xor(acc.y, 32, 64);
    acc.z += __shfl_xor(acc.z, 32, 64);
    acc.w += __shfl_xor(acc.w, 32, 64);
    if ((tid & 63) < 32) red[tid >> 6][tc] = acc;
    __syncthreads();
    if (tid < 32) {
        vf4 c = red[0][tid];
#pragma unroll
        for (int rr = 1; rr < 16; ++rr) c += red[rr][tid];
        contrS[tid] = c;
    }
    __syncthreads();
    vf4 contr = contrS[tc];

    float al_i = ws[OFF_AL + hi];
    float ba_i = ws[OFF_BA + hi];

    float coef = 0.f, bsd_i = 0.f, u_i = 0.f;
    vf4 scol = {0.f, 0.f, 0.f, 0.f};
    float srow[4];
    int ic = i >> 2, icomp = i & 3;

    if (t == 0)      coef = ws[OFF_CW + hi];
    else if (t == 2) coef = ws[OFF_CB + hi];
    else if (t == 3) coef = ws[OFF_CV + hi];
    else if (t == 1) {
        coef  = ws[OFF_ALP + hi];
        bsd_i = ws[OFF_BSD + hi];
        if (tc == ic) {
#pragma unroll
            for (int m = 0; m < 4; ++m)
                srow[m] = S[(size_t)hi * 128 + tj + (m << 5)];
        }
    } else { // t == 4
        u_i  = ws[OFF_U + hi];
        scol = reinterpret_cast<const vf4*>(S + (size_t)hi * 128)[tc];
    }

    // pass 2: out[j][c] = al*P - ba*k[j]*contr[c] + D-term  (nontemporal store)
    vf4* O4 = reinterpret_cast<vf4*>(O);
#pragma unroll
    for (int m = 0; m < 4; ++m) {
        int j = tj + (m << 5);
        float kj = kkf[j];
        vf4 o = al_i * p[m] - (ba_i * kj) * contr;
        if (t == 4) {
            o -= (ba_i * kj) * scol;              // -ba[i]*S[i,c]*k[j]
            if ((j >> 2) == tc) o[j & 3] += u_i;  // +u[i]*eye[j,c]
        } else if (t == 1) {
            if (tc == ic) o[icomp] += coef * (srow[m] - bsd_i * kj);
        } else {
            if (tc == ic) o[icomp] += coef * kj;  // eye[i,c] * coef * k[j]
        }
        __builtin_nontemporal_store(o, O4 + j * 32 + tc);
    }
}

// ---- K4: y = W_o @ y_heads + b_o. grid = 128 blocks x 256 threads ----
__global__ __launch_bounds__(256) void k_out(
    const float* __restrict__ Wo, const float* __restrict__ bo,
    const float* __restrict__ ws, float* __restrict__ out)
{
    int wave = threadIdx.x >> 6;
    int lane = threadIdx.x & 63;
    int o = blockIdx.x * 4 + wave;     // 0..511
    const float* wr = Wo + (size_t)o * 1024;
    const float* yh = ws + OFF_YH;
    float s = 0.f;
#pragma unroll
    for (int e = 0; e < 16; ++e)
        s += wr[lane + 64 * e] * yh[lane + 64 * e];
#pragma unroll
    for (int off = 32; off; off >>= 1)
        s += __shfl_down(s, off, 64);
    if (lane == 0) out[o] = s + bo[o];
}

extern "C" void kernel_launch(void* const* d_in, const int* in_sizes, int n_in,
                              void* d_out, int out_size, void* d_ws, size_t ws_size,
                              hipStream_t stream)
{
    const float* x   = (const float*)d_in[0];
    const float* S   = (const float*)d_in[1];
    const float* smw = (const float*)d_in[2];
    const float* smz = (const float*)d_in[3];
    const float* smb = (const float*)d_in[4];
    const float* smv = (const float*)d_in[5];
    const float* smk = (const float*)d_in[6];
    const float* Ww  = (const float*)d_in[7];
    const float* Wz  = (const float*)d_in[8];
    const float* Wb  = (const float*)d_in[9];
    const float* Wv  = (const float*)d_in[10];
    const float* Wk  = (const float*)d_in[11];
    const float* Wq  = (const float*)d_in[12];
    const float* Wo  = (const float*)d_in[13];
    const float* bo  = (const float*)d_in[14];

    float* out = (float*)d_out;
    float* ws  = (float*)d_ws;

    k_proj<<<1312, 256, 0, stream>>>(x, Ww, Wz, Wb, Wv, Wk, Wq, ws);
    k_head<<<8, 128, 0, stream>>>(S, ws, out);
    k_main<<<5120, 1024, 0, stream>>>(smw, smz, smb, smv, smk, S, ws, out);
    k_out<<<128, 256, 0, stream>>>(Wo, bo, ws, out);
}